// Round 12
// baseline (3738.971 us; speedup 1.0000x reference)
//
#include <hip/hip_runtime.h>
#include <hip/hip_fp16.h>

// Unidir_LSTM: h_t = sig(o)*tanh(sig(i)*tanh(g)); f-gate dead (cell carry always 0).
// R16 — INTRA-STEP PHASE ABLATION. R15 post-mortem: the "DVFS/725MHz" theory was
//   MY CONSTANT ERROR (ERRATA #10): m06's 4.85cy/MFMA is per-CU; per-SIMD a
//   16x16x32 f16 MFMA is ~19.4cy. Redone: clock ~2.3-2.4GHz (no DVFS issue; warmup
//   null confirmed, pump moot). Step = ~10,200cy of which modeled phases cover
//   ~3,000: MFMA ~1,200 + loads ~500 + reduce ~400 + epi ~250 + stores ~400 +
//   barriers ~300, poll ~0 (R12). ~7,000cy/step (70%) is UNEXPLAINED. R12 proved
//   it's intra-block. Suspects: MFMA operand marshalling (AGPR moves), back-half
//   chain, VMEM batching, inter-phase waitcnt serialization. MfmaUtil (gfx94x
//   fallback formula) may itself mislead.
//   Five dispatches (per-dispatch rows in rocprof; V0 keeps round correct):
//     V0: R13-exact real (writes out)           ~1086us anchor
//     A:  free-run skeleton (no poll/release; h from L2-resident t&1 scratch slab)
//     B:  A minus ALL MFMAs (loads kept, asm-sunk per rule #17)
//     C:  A minus back-half (no ds/barrier/reduce/epi/store; acc sunk; LDS=0 marks row)
//     D:  A minus VMEM loads (operands from resident regs; back-half kept)
//   Committed rules: Delta(A-B)=MFMA cost, Delta(A-C)=back-half, Delta(A-D)=loads.
//   Any Delta>300us => that phase is next round's sole target. All Delta<150us &&
//   A~V0 => phase-coupling (waitcnt batching) => software-pipeline phases next.
//   Total ~5.5ms this round — accepted diagnostic cost (R12 precedent paid off).

typedef __fp16 f16x8 __attribute__((ext_vector_type(8)));
typedef __fp16 f16x4 __attribute__((ext_vector_type(4)));
typedef float  f32x4 __attribute__((ext_vector_type(4)));

#define MFMA16(a, b, c) __builtin_amdgcn_mfma_f32_16x16x32_f16(a, b, c, 0, 0, 0)

__device__ __forceinline__ float sigmoid_f(float x) {
  return 1.f / (1.f + __expf(-x));
}
__device__ __forceinline__ float tanh_f(float x) {
  x = fminf(fmaxf(x, -15.f), 15.f);
  float e = __expf(2.f * x);
  return (e - 1.f) / (e + 1.f);
}

static constexpr int SS = 256;

// ---------------- prep: pack W_ih/W_hh rows {i,g,o} to fp16, bias3 = b_ih+b_hh ----
__global__ void prep_kernel(const float* __restrict__ W_ih, const float* __restrict__ W_hh,
                            const float* __restrict__ b_ih, const float* __restrict__ b_hh,
                            __fp16* __restrict__ Wi3, __fp16* __restrict__ Wh3,
                            float* __restrict__ bias3) {
  int j3 = blockIdx.x;                 // 0..3071 packed row
  int g = j3 >> 10, j = j3 & 1023;
  int orig = (g == 0 ? 0 : (g == 1 ? 2048 : 3072)) + j;  // i,g,o rows of 4H
  int tid = threadIdx.x;
  {
    float4 v = *(const float4*)(W_hh + (size_t)orig * 1024 + tid * 4);
    f16x4 o = {(__fp16)v.x, (__fp16)v.y, (__fp16)v.z, (__fp16)v.w};
    *(f16x4*)(Wh3 + (size_t)j3 * 1024 + tid * 4) = o;
  }
  if (tid < 128) {
    float4 v = *(const float4*)(W_ih + (size_t)orig * 512 + tid * 4);
    f16x4 o = {(__fp16)v.x, (__fp16)v.y, (__fp16)v.z, (__fp16)v.w};
    *(f16x4*)(Wi3 + (size_t)j3 * 512 + tid * 4) = o;
  }
  if (tid == 0) bias3[j3] = b_ih[orig] + b_hh[orig];
}

// ---------------- gather: X[t*128+b][e] = fp16(embed[tok[b][t]][e]) ----------------
__global__ void gather_kernel(const int* __restrict__ tok, const float* __restrict__ emb,
                              __fp16* __restrict__ X) {
  int m = blockIdx.x;                  // 0..32767 = t*128 + b
  int t = m >> 7, b = m & 127;
  int tk = tok[b * SS + t];            // inputs is [B][S]
  int e0 = threadIdx.x * 8;
  const float* src = emb + (size_t)tk * 512 + e0;
  float4 v0 = *(const float4*)src;
  float4 v1 = *(const float4*)(src + 4);
  f16x8 o;
  o[0] = (__fp16)v0.x; o[1] = (__fp16)v0.y; o[2] = (__fp16)v0.z; o[3] = (__fp16)v0.w;
  o[4] = (__fp16)v1.x; o[5] = (__fp16)v1.y; o[6] = (__fp16)v1.z; o[7] = (__fp16)v1.w;
  *(f16x8*)(X + (size_t)m * 512 + e0) = o;
}

// ---------------- recurrence: R13 structure, templated phase ablation -------------
// MODE 0: real (R13-exact; poll+release; writes real out).
// MODE 1: free-run skeleton — no poll/release; h loads from (t&1) slab (L2-res).
// MODE 2: MODE1 minus all MFMAs (xa/ha loads kept + asm-sunk; acc stays 0).
// MODE 3: MODE1 minus back-half (no ds_write/barrier/reduce/epilogue/store; acc sunk).
// MODE 4: MODE1 minus VMEM loads (operands = resident weight regs; back-half kept).
template <int MODE>
__global__ __launch_bounds__(512, 2) void recur_t(const __fp16* __restrict__ Wh3,
                                                  const __fp16* __restrict__ Wi3,
                                                  const __fp16* __restrict__ X,
                                                  const float* __restrict__ bias3,
                                                  __fp16* __restrict__ hbuf,
                                                  int* __restrict__ cnt,
                                                  float* __restrict__ out) {
  const int bid = blockIdx.x;
  const int bg = bid & 7, n = bid >> 3;   // XCD-local batch groups
  const int b0 = bg * 16, j0 = n * 32;
  const int tid = threadIdx.x, wid = tid >> 6, lane = tid & 63;
  const int l15 = lane & 15, quad = lane >> 4;
  const int kq = wid >> 1, ct = wid & 1;  // compute ownership: K-quarter, col-tile
  const int ct_e = wid & 1, rq = wid >> 1;  // epilogue ownership
  const int lr = lane >> 4;

  __shared__ float gbuf[2][4][3][2][16][20];

  // persistent B fragments (col = j0 + ct*16 + l15, k = kq*256 + kk*32 + quad*8)
  f16x8 wh[3][8];
  f16x8 wi[3][4];
#pragma unroll
  for (int g = 0; g < 3; ++g) {
    const __fp16* wr = Wh3 + (size_t)(g * 1024 + j0 + ct * 16 + l15) * 1024 + kq * 256 + quad * 8;
#pragma unroll
    for (int kk = 0; kk < 8; ++kk) wh[g][kk] = *(const f16x8*)(wr + kk * 32);
    const __fp16* wr2 = Wi3 + (size_t)(g * 1024 + j0 + ct * 16 + l15) * 512 + kq * 128 + quad * 8;
#pragma unroll
    for (int kk = 0; kk < 4; ++kk) wi[g][kk] = *(const f16x8*)(wr2 + kk * 32);
  }

  float bs[3];
#pragma unroll
  for (int g = 0; g < 3; ++g) bs[g] = bias3[g * 1024 + j0 + ct_e * 16 + l15];

  const __fp16* xrow = X + (size_t)(b0 + l15) * 512 + kq * 128 + quad * 8;
  const __fp16* hrow = hbuf + (size_t)(b0 + l15) * 1024 + kq * 256 + quad * 8;
  int* cbase = cnt + bg * (SS * 16);      // one 64B line per (bg, t)

  // A-frag registers. MODE 4: filled once from resident weights (no VMEM in loop).
  f16x8 xa[4];
  f16x8 ha[8];
  if constexpr (MODE == 4) {
#pragma unroll
    for (int kk = 0; kk < 4; ++kk) xa[kk] = wi[0][kk];
#pragma unroll
    for (int kk = 0; kk < 8; ++kk) ha[kk] = wh[1][kk];
  } else {
#pragma unroll
    for (int kk = 0; kk < 4; ++kk) xa[kk] = *(const f16x8*)(xrow + kk * 32);
  }

  for (int t = 0; t < SS; ++t) {
    f32x4 acc[3];
#pragma unroll
    for (int g = 0; g < 3; ++g) {
      f32x4 z = {0.f, 0.f, 0.f, 0.f};
      acc[g] = z;
    }
    // (a) X-MFMAs (h-independent, before the poll)
    if constexpr (MODE != 2) {
#pragma unroll
      for (int kk = 0; kk < 4; ++kk)
#pragma unroll
        for (int g = 0; g < 3; ++g)
          acc[g] = MFMA16(xa[kk], wi[g][kk], acc[g]);
    }
    // (a2) prefetch X for t+1 (skip in no-VMEM mode)
    if constexpr (MODE != 4) {
      const int tn = (t + 1 < SS) ? t + 1 : t;
      const __fp16* xp = xrow + (size_t)tn * 65536;
#pragma unroll
      for (int kk = 0; kk < 4; ++kk) xa[kk] = *(const f16x8*)(xp + kk * 32);
      if constexpr (MODE == 2) {
#pragma unroll
        for (int kk = 0; kk < 4; ++kk) asm volatile("" :: "v"(xa[kk]));
      }
    }
    // (b) poll — real mode only (R12: costs ~0)
    if constexpr (MODE == 0) {
      if (t > 0) {
        const int* pollp = cbase + t * 16;
        for (;;) {
          int v = __hip_atomic_load(pollp, __ATOMIC_RELAXED, __HIP_MEMORY_SCOPE_AGENT);
          if (v >= 32) break;
          __builtin_amdgcn_s_sleep(1);
        }
        asm volatile("" ::: "memory");
      }
    }
    // (c) h A-frags. MODE 0: real step slab (XCD-L2 hit). MODE 1/2/3: (t&1) slab
    //     of scratch (512KB, L2-resident; t-dependent so not hoistable).
    if constexpr (MODE != 4) {
      const __fp16* hp = (MODE == 0) ? hrow + (size_t)t * 131072
                                     : hrow + (size_t)(t & 1) * 131072;
#pragma unroll
      for (int kk = 0; kk < 8; ++kk) ha[kk] = *(const f16x8*)(hp + kk * 32);
      if constexpr (MODE == 2) {
#pragma unroll
        for (int kk = 0; kk < 8; ++kk) asm volatile("" :: "v"(ha[kk]));
      }
    }
    // (d) h-MFMAs
    if constexpr (MODE != 2) {
#pragma unroll
      for (int kk = 0; kk < 8; ++kk)
#pragma unroll
        for (int g = 0; g < 3; ++g)
          acc[g] = MFMA16(ha[kk], wh[g][kk], acc[g]);
    }
    // (e) back-half: publish partials, barrier, reduce, epilogue, store
    if constexpr (MODE != 3) {
      const int tp = t & 1;
#pragma unroll
      for (int g = 0; g < 3; ++g)
#pragma unroll
        for (int r = 0; r < 4; ++r)
          gbuf[tp][kq][g][ct][quad * 4 + r][l15] = acc[g][r];
      __syncthreads();
      {
        const int row_i = rq * 4 + lr;
        float s[3];
#pragma unroll
        for (int g = 0; g < 3; ++g)
          s[g] = gbuf[tp][0][g][ct_e][row_i][l15] + gbuf[tp][1][g][ct_e][row_i][l15] +
                 gbuf[tp][2][g][ct_e][row_i][l15] + gbuf[tp][3][g][ct_e][row_i][l15];
        float gi = s[0] + bs[0];
        float gg = s[1] + bs[1];
        float go = s[2] + bs[2];
        float cv = sigmoid_f(gi) * tanh_f(gg);
        float hN = sigmoid_f(go) * tanh_f(cv);
        const int row = b0 + row_i;
        const int col = j0 + ct_e * 16 + l15;
        if (t == SS - 1) out[(size_t)row * 1024 + col] = hN;
        else hbuf[(size_t)(t + 1) * 131072 + (size_t)row * 1024 + col] = (__fp16)hN;
      }
    } else {
#pragma unroll
      for (int g = 0; g < 3; ++g) asm volatile("" :: "v"(acc[g]));
    }
    // (f) release — real mode only (R12: costs ~0)
    if constexpr (MODE == 0) {
      if (t < SS - 1) {
        asm volatile("s_waitcnt vmcnt(0)" ::: "memory");
        __syncthreads();
        if (tid == 0)
          __hip_atomic_fetch_add(cbase + (t + 1) * 16, 1,
                                 __ATOMIC_RELAXED, __HIP_MEMORY_SCOPE_AGENT);
      }
    }
  }
}

extern "C" void kernel_launch(void* const* d_in, const int* in_sizes, int n_in,
                              void* d_out, int out_size, void* d_ws, size_t ws_size,
                              hipStream_t stream) {
  const int*   tok  = (const int*)d_in[0];
  const float* emb  = (const float*)d_in[1];
  const float* W_ih = (const float*)d_in[2];
  const float* W_hh = (const float*)d_in[3];
  const float* b_ih = (const float*)d_in[4];
  const float* b_hh = (const float*)d_in[5];
  float* out = (float*)d_out;
  char* ws = (char*)d_ws;

  // ws layout (bytes), total ~178 MB (prior sessions used up to 297 MB)
  __fp16* X     = (__fp16*)(ws + 0);              // 33,554,432
  __fp16* Wi3   = (__fp16*)(ws + 33554432);       //  3,145,728
  __fp16* Wh3   = (__fp16*)(ws + 36700160);       //  6,291,456
  float*  bias3 = (float*) (ws + 42991616);       //     12,288
  int*    cnt   = (int*)   (ws + 43003904);       //    131,072 (8 grp x 256 t, 64B lines)
  __fp16* hbuf  = (__fp16*)(ws + 43134976);       // 67,108,864 (256 step buffers)
  int*    cnt2  = (int*)   (ws + 110243840);      //    131,072 (scratch, unused by free-runs)
  __fp16* hbuf2 = (__fp16*)(ws + 110374912);      // 67,108,864 (scratch h for A/B/C)
  float*  out2  = (float*) (ws + 177483776);      //    524,288 (scratch out)

  (void)hipMemsetAsync(cnt, 0, 131072, stream);
  (void)hipMemsetAsync(hbuf, 0, 131072 * 2, stream);   // h_0 = 0
  (void)hipMemsetAsync(hbuf2, 0, 131072 * 4, stream);  // zero both (t&1) slabs

  prep_kernel<<<3072, 256, 0, stream>>>(W_ih, W_hh, b_ih, b_hh, Wi3, Wh3, bias3);
  gather_kernel<<<32768, 64, 0, stream>>>(tok, emb, X);
  // V0: real (R13-exact), writes `out` — the correctness anchor.
  recur_t<0><<<256, 512, 0, stream>>>(Wh3, Wi3, X, bias3, hbuf, cnt, out);
  // A: free-run skeleton. B: -MFMA. C: -backhalf (LDS=0 marks its row). D: -VMEM.
  recur_t<1><<<256, 512, 0, stream>>>(Wh3, Wi3, X, bias3, hbuf2, cnt2, out2);
  recur_t<2><<<256, 512, 0, stream>>>(Wh3, Wi3, X, bias3, hbuf2, cnt2, out2);
  recur_t<3><<<256, 512, 0, stream>>>(Wh3, Wi3, X, bias3, hbuf2, cnt2, out2);
  recur_t<4><<<256, 512, 0, stream>>>(Wh3, Wi3, X, bias3, hbuf2, cnt2, out2);
}

// Round 13
// 1786.194 us; speedup vs baseline: 2.0933x; 2.0933x over previous
//
#include <hip/hip_runtime.h>
#include <hip/hip_fp16.h>

// Unidir_LSTM: h_t = sig(o)*tanh(sig(i)*tanh(g)); f-gate dead (cell carry always 0).
// R17: R16 ablation read via the TOTAL (top-5 only shows the slowest type): A+B+C+D
//   ~2564us; additive phases => 3A + P_rest = 2564 => free-run A <= ~820us (top-5
//   rows were all V0). Therefore: (1) the 8-wave R13 handoff costs ~300us (R12's
//   4-wave was ~0); (2) the ~500-650us of phase cost above the ~250us instruction
//   model is DISTRIBUTED across MFMA/loads/back-half => phase-boundary
//   serialization (each phase ends in a waitcnt/barrier drain; 2 waves/SIMD can't
//   hide it). Fix = fewer phases, fewer coupled waves:
//   - 256 blocks x 256 thr, launch_bounds(256,1): 4 waves = (tile 0-1) x (K-half
//     0-1), 1 wave/SIMD, ~426 unified regs/wave (weights 288 -> AGPR side).
//   - Per wave 3 gates x K=768 resident: 72 MFMA/step; ONE barrier/step; kh1 does
//     reduce+epilogue+store+own-vmcnt-drain+lane0 fetch_add (wave-autonomous
//     release, threshold 64) while kh0 rolls into t+1's X-MFMAs.
//   - Epilogue: __builtin_amdgcn_rcpf kills 4 full-div sequences per h-value.
// Predict: recur 1085 -> 450-700us (total 600-850), MfmaUtil 11.5 -> 30-50% (THE
//   signature), Occupancy ~12.5%, LDS 15360, FETCH ~86MB, WRITE ~68MB (jump =
//   spill alarm). recur >=950 & MfmaUtil ~12% => phase-merge refuted, suspect
//   clock (R15 pump read ~1.0-1.2GHz, which would explain the residual gap).

typedef __fp16 f16x8 __attribute__((ext_vector_type(8)));
typedef __fp16 f16x4 __attribute__((ext_vector_type(4)));
typedef float  f32x4 __attribute__((ext_vector_type(4)));

#define MFMA16(a, b, c) __builtin_amdgcn_mfma_f32_16x16x32_f16(a, b, c, 0, 0, 0)

__device__ __forceinline__ float rcp_f(float x) { return __builtin_amdgcn_rcpf(x); }
__device__ __forceinline__ float sigmoid_f(float x) {
  return rcp_f(1.f + __expf(-x));
}
__device__ __forceinline__ float tanh_f(float x) {
  x = fminf(fmaxf(x, -15.f), 15.f);
  float e = __expf(2.f * x);
  return 1.f - 2.f * rcp_f(e + 1.f);
}

static constexpr int SS = 256;

// ---------------- prep: pack W_ih/W_hh rows {i,g,o} to fp16, bias3 = b_ih+b_hh ----
__global__ void prep_kernel(const float* __restrict__ W_ih, const float* __restrict__ W_hh,
                            const float* __restrict__ b_ih, const float* __restrict__ b_hh,
                            __fp16* __restrict__ Wi3, __fp16* __restrict__ Wh3,
                            float* __restrict__ bias3) {
  int j3 = blockIdx.x;                 // 0..3071 packed row
  int g = j3 >> 10, j = j3 & 1023;
  int orig = (g == 0 ? 0 : (g == 1 ? 2048 : 3072)) + j;  // i,g,o rows of 4H
  int tid = threadIdx.x;
  {
    float4 v = *(const float4*)(W_hh + (size_t)orig * 1024 + tid * 4);
    f16x4 o = {(__fp16)v.x, (__fp16)v.y, (__fp16)v.z, (__fp16)v.w};
    *(f16x4*)(Wh3 + (size_t)j3 * 1024 + tid * 4) = o;
  }
  if (tid < 128) {
    float4 v = *(const float4*)(W_ih + (size_t)orig * 512 + tid * 4);
    f16x4 o = {(__fp16)v.x, (__fp16)v.y, (__fp16)v.z, (__fp16)v.w};
    *(f16x4*)(Wi3 + (size_t)j3 * 512 + tid * 4) = o;
  }
  if (tid == 0) bias3[j3] = b_ih[orig] + b_hh[orig];
}

// ---------------- gather: X[t*128+b][e] = fp16(embed[tok[b][t]][e]) ----------------
__global__ void gather_kernel(const int* __restrict__ tok, const float* __restrict__ emb,
                              __fp16* __restrict__ X) {
  int m = blockIdx.x;                  // 0..32767 = t*128 + b
  int t = m >> 7, b = m & 127;
  int tk = tok[b * SS + t];            // inputs is [B][S]
  int e0 = threadIdx.x * 8;
  const float* src = emb + (size_t)tk * 512 + e0;
  float4 v0 = *(const float4*)src;
  float4 v1 = *(const float4*)(src + 4);
  f16x8 o;
  o[0] = (__fp16)v0.x; o[1] = (__fp16)v0.y; o[2] = (__fp16)v0.z; o[3] = (__fp16)v0.w;
  o[4] = (__fp16)v1.x; o[5] = (__fp16)v1.y; o[6] = (__fp16)v1.z; o[7] = (__fp16)v1.w;
  *(f16x8*)(X + (size_t)m * 512 + e0) = o;
}

// ---------------- recurrence: K-half merge, 1 wave/SIMD, 1 barrier/step ----------
// 256 blocks = (bg 0..7: 16 batch rows, XCD-pinned via bid&7, 32 blocks = 32 CUs
// per XCD, 1 block/CU) x (n 0..31: 32 h-cols). 4 waves = (tile 0-1: 16 cols) x
// (kh 0-1: K-half; X 256 each, h 512 each). Per wave resident: wi[3][8] (96) +
// wh[3][16] (192) = 288 regs (AGPR side), ha[16]=64, xa[8]=32, acc 12.
// Per step: 24 X-MFMAs (pre-poll) -> prefetch xa(t+1) -> poll(t) thr 64 ->
// ha loads -> 48 h-MFMAs -> kh0: 12 ds_writes / barrier / kh1: 12 ds_reads +
// add + epilogue(rcp) + 4 stores + own vmcnt(0) + lane0 agent fetch_add(t+1).
// kh0 waves pass the barrier and immediately start t+1's X-MFMAs (overlap).
__global__ __launch_bounds__(256, 1) void recur_kernel(const __fp16* __restrict__ Wh3,
                                                       const __fp16* __restrict__ Wi3,
                                                       const __fp16* __restrict__ X,
                                                       const float* __restrict__ bias3,
                                                       __fp16* __restrict__ hbuf,
                                                       int* __restrict__ cnt,
                                                       float* __restrict__ out) {
  const int bid = blockIdx.x;
  const int bg = bid & 7, n = bid >> 3;   // XCD-local batch groups
  const int b0 = bg * 16, j0 = n * 32;
  const int tid = threadIdx.x, wid = tid >> 6, lane = tid & 63;
  const int l15 = lane & 15, quad = lane >> 4;
  const int tile = wid & 1, kh = wid >> 1;  // col-tile, K-half
  const int col = j0 + tile * 16 + l15;

  // kh0 -> kh1 partial exchange; row stride 20 floats -> 2-way banks (free, m136)
  __shared__ float gbuf[2][2][3][16][20];

  // persistent B fragments: full 3 gates x K-half (X 256 + h 512)
  f16x8 wi[3][8];
  f16x8 wh[3][16];
#pragma unroll
  for (int g = 0; g < 3; ++g) {
    const __fp16* wr2 = Wi3 + (size_t)(g * 1024 + col) * 512 + kh * 256 + quad * 8;
#pragma unroll
    for (int kk = 0; kk < 8; ++kk) wi[g][kk] = *(const f16x8*)(wr2 + kk * 32);
    const __fp16* wr = Wh3 + (size_t)(g * 1024 + col) * 1024 + kh * 512 + quad * 8;
#pragma unroll
    for (int kk = 0; kk < 16; ++kk) wh[g][kk] = *(const f16x8*)(wr + kk * 32);
  }

  float bs[3];
#pragma unroll
  for (int g = 0; g < 3; ++g) bs[g] = bias3[g * 1024 + col];

  const __fp16* xrow = X + (size_t)(b0 + l15) * 512 + kh * 256 + quad * 8;
  const __fp16* hrow = hbuf + (size_t)(b0 + l15) * 1024 + kh * 512 + quad * 8;
  int* cbase = cnt + bg * (SS * 16);      // one 64B line per (bg, t)

  // preload X A-frags for t=0
  f16x8 xa[8];
#pragma unroll
  for (int kk = 0; kk < 8; ++kk) xa[kk] = *(const f16x8*)(xrow + kk * 32);

  for (int t = 0; t < SS; ++t) {
    // (a) X-MFMAs on prefetched frags — h-independent, before the poll
    f32x4 acc[3];
#pragma unroll
    for (int g = 0; g < 3; ++g) {
      f32x4 z = {0.f, 0.f, 0.f, 0.f};
      acc[g] = z;
    }
#pragma unroll
    for (int kk = 0; kk < 8; ++kk)
#pragma unroll
      for (int g = 0; g < 3; ++g)
        acc[g] = MFMA16(xa[kk], wi[g][kk], acc[g]);
    // (a2) prefetch X for t+1; latency retires under poll + h-phase
    {
      const int tn = (t + 1 < SS) ? t + 1 : t;
      const __fp16* xp = xrow + (size_t)tn * 65536;
#pragma unroll
      for (int kk = 0; kk < 8; ++kk) xa[kk] = *(const f16x8*)(xp + kk * 32);
    }
    // (b) wait for the 64 producer kh1-waves of our batch group (agent relaxed
    //     load of one aggregated counter; hang-proof R9 primitive)
    if (t > 0) {
      const int* pollp = cbase + t * 16;
      for (;;) {
        int v = __hip_atomic_load(pollp, __ATOMIC_RELAXED, __HIP_MEMORY_SCOPE_AGENT);
        if (v >= 64) break;
        __builtin_amdgcn_s_sleep(1);
      }
      asm volatile("" ::: "memory");
    }
    // (c) h A-frags global->VGPR (XCD-L2 hit), then 48 h-MFMAs
    f16x8 ha[16];
    {
      const __fp16* hp = hrow + (size_t)t * 131072;
#pragma unroll
      for (int kk = 0; kk < 16; ++kk) ha[kk] = *(const f16x8*)(hp + kk * 32);
    }
#pragma unroll
    for (int kk = 0; kk < 16; ++kk)
#pragma unroll
      for (int g = 0; g < 3; ++g)
        acc[g] = MFMA16(ha[kk], wh[g][kk], acc[g]);
    // (d) kh0 publishes partials; ONE barrier; kh1 finishes the step entirely.
    const int tp = t & 1;
    if (kh == 0) {
#pragma unroll
      for (int g = 0; g < 3; ++g)
#pragma unroll
        for (int r = 0; r < 4; ++r)
          gbuf[tp][tile][g][quad * 4 + r][l15] = acc[g][r];
    }
    __syncthreads();
    if (kh == 1) {
#pragma unroll
      for (int r = 0; r < 4; ++r) {
        const int row_i = quad * 4 + r;
        float gi = acc[0][r] + gbuf[tp][tile][0][row_i][l15] + bs[0];
        float gg = acc[1][r] + gbuf[tp][tile][1][row_i][l15] + bs[1];
        float go = acc[2][r] + gbuf[tp][tile][2][row_i][l15] + bs[2];
        float cv = sigmoid_f(gi) * tanh_f(gg);
        float hN = sigmoid_f(go) * tanh_f(cv);
        const int row = b0 + row_i;
        if (t == SS - 1) out[(size_t)row * 1024 + col] = hN;
        else hbuf[(size_t)(t + 1) * 131072 + (size_t)row * 1024 + col] = (__fp16)hN;
      }
      // wave-autonomous release: drain OWN stores into the XCD L2, then lane0
      // bumps the (bg, t+1) counter (agent RMW at the MALL, device-visible).
      // kh0 waves are already running t+1's X-MFMAs — no release barrier.
      if (t < SS - 1) {
        asm volatile("s_waitcnt vmcnt(0)" ::: "memory");
        if (lane == 0)
          __hip_atomic_fetch_add(cbase + (t + 1) * 16, 1,
                                 __ATOMIC_RELAXED, __HIP_MEMORY_SCOPE_AGENT);
      }
    }
  }
}

extern "C" void kernel_launch(void* const* d_in, const int* in_sizes, int n_in,
                              void* d_out, int out_size, void* d_ws, size_t ws_size,
                              hipStream_t stream) {
  const int*   tok  = (const int*)d_in[0];
  const float* emb  = (const float*)d_in[1];
  const float* W_ih = (const float*)d_in[2];
  const float* W_hh = (const float*)d_in[3];
  const float* b_ih = (const float*)d_in[4];
  const float* b_hh = (const float*)d_in[5];
  float* out = (float*)d_out;
  char* ws = (char*)d_ws;

  // ws layout (bytes), total 110,243,840 (~105 MB)
  __fp16* X     = (__fp16*)(ws + 0);              // 33,554,432
  __fp16* Wi3   = (__fp16*)(ws + 33554432);       //  3,145,728
  __fp16* Wh3   = (__fp16*)(ws + 36700160);       //  6,291,456
  float*  bias3 = (float*) (ws + 42991616);       //     12,288
  int*    cnt   = (int*)   (ws + 43003904);       //    131,072 (8 grp x 256 t, 64B lines)
  __fp16* hbuf  = (__fp16*)(ws + 43134976);       // 67,108,864 (256 step buffers)

  (void)hipMemsetAsync(cnt, 0, 131072, stream);
  (void)hipMemsetAsync(hbuf, 0, 131072 * 2, stream);  // h_0 = 0

  prep_kernel<<<3072, 256, 0, stream>>>(W_ih, W_hh, b_ih, b_hh, Wi3, Wh3, bias3);
  gather_kernel<<<32768, 64, 0, stream>>>(tok, emb, X);
  recur_kernel<<<256, 256, 0, stream>>>(Wh3, Wi3, X, bias3, hbuf, cnt, out);
}